// Round 8
// baseline (2064.196 us; speedup 1.0000x reference)
//
#include <hip/hip_runtime.h>

typedef __attribute__((ext_vector_type(8))) short bfrag8;   // 8 bf16 (4 VGPR)
typedef __attribute__((ext_vector_type(4))) float f32x4;    // MFMA acc

// Problem constants
#define N_TH   4609      // D_THETA
#define NIB    289       // i-blocks of 16 (289*16 = 4624)
#define NKC    152       // j-chunks of 32 (8*19; chunks >=145 are zero pad)
#define TSTR   4612      // theta row stride (floats)
#define NB     32
#define NL     32

// ws layout (float offsets); total 13,334,504 fl = 53.34 MB (< proven 55.02 MB)
#define OF_PROW  0          // 4624*12 = 55,488
#define OF_PMF   55488      // 2 x 152*512 ushort = 77,824 fl
#define OF_CNT   133312     // 296 (289 ints)
#define OF_PCOLB 133608     // 32*4624 = 147,968
#define OF_PMCH  281576     // 10*289*512 ushort = 739,840 fl
#define OF_PMCL  1021416    // 739,840 fl
#define OF_CFH   1761256    // 10*64*512 ushort = 163,840 fl
#define OF_CFL   1925096    // 163,840 fl
#define OF_A2M   2088936    // 289*152*512 ushort = 11,245,568 fl ; theta aliases

__device__ __forceinline__ unsigned short f2bf(float v) {
    unsigned int u = __float_as_uint(v);
    return (unsigned short)((u + 0x7fffu + ((u >> 16) & 1u)) >> 16);  // RNE
}
__device__ __forceinline__ float bf2f(unsigned short h) {
    return __uint_as_float((unsigned int)h << 16);
}

// ---------------------------------------------------------------------------
// P_0: Prow fp32, scan B-frags (Pmf buf0; buf1 zeroed), conv B-frags plane j=0,
// and zero the arrival counters. idx over 4864*16 = 77,824.
__global__ __launch_bounds__(256) void k_p0(const float* __restrict__ th0,
                                            const float* __restrict__ Bm,
                                            float* __restrict__ Prow,
                                            unsigned short* __restrict__ Pmf,
                                            unsigned short* __restrict__ PmcH,
                                            unsigned short* __restrict__ PmcL,
                                            int* __restrict__ cnt) {
    int idx = blockIdx.x * 256 + threadIdx.x;
    if (idx >= NKC * 32 * 16) return;
    int i = idx >> 4, c = idx & 15;
    float v = 0.f;
    if (i < N_TH && c < 11) {
        if (c == 0) v = th0[i];
        else v = Bm[(size_t)i * 10 + (c - 1)];
    }
    if (i < 4624 && c < 12) Prow[i * 12 + c] = v;
    // scan B-frag slot
    int ch = i >> 5, kr = i & 31;
    size_t slot = (size_t)ch * 512 + (size_t)(((kr >> 3) * 16 + c) << 3) + (kr & 7);
    Pmf[slot] = (v == 0.f) ? (unsigned short)0 : f2bf(v);
    Pmf[(size_t)NKC * 512 + slot] = 0;
    // conv B-frag plane j=0 (kidx = c-1, kc=0)
    if (c >= 1 && c <= 10 && i < N_TH) {
        int kidx = c - 1;
        size_t s2 = ((size_t)(i >> 4) << 9) +
                    (size_t)((((kidx & 31) >> 3) * 16 + (i & 15)) << 3) + (kidx & 7);
        unsigned short h = f2bf(v);
        PmcH[s2] = h;
        PmcL[s2] = f2bf(v - bf2f(h));
    }
    if (idx < NIB) cnt[idx] = 0;
}

// ---------------------------------------------------------------------------
// du-coef -> conv A-frags (hi/lo), computed directly from xs/ts.
// idx over 10*64*512 = 327,680.
__global__ __launch_bounds__(256) void k_cf(const float* __restrict__ xs,
                                            const float* __restrict__ ts,
                                            unsigned short* __restrict__ CfH,
                                            unsigned short* __restrict__ CfL) {
    int idx = blockIdx.x * 256 + threadIdx.x;
    if (idx >= 10 * 64 * 512) return;
    int kk = idx & 7;
    int l  = (idx >> 3) & 63;
    int mt = (idx >> 9) & 63;
    int kc = idx >> 15;
    int bt = mt * 16 + (l & 15);
    int t = bt & 31, b = bt >> 5;
    int kidx = kc * 32 + (l >> 4) * 8 + kk;
    int j = kidx / 10, d = kidx - j * 10;
    float v = 0.f;
    if (j < t) {
        int tt = t - j;   // >= 1
        v = (d == 0) ? (ts[b * NL + tt] - ts[b * NL + tt - 1])
                     : (xs[(size_t)(b * NL + tt) * 9 + d - 1] -
                        xs[(size_t)(b * NL + tt - 1) * 9 + d - 1]);
    }
    unsigned short h = f2bf(v);
    CfH[idx] = h;
    CfL[idx] = f2bf(v - bf2f(h));
}

// ---------------------------------------------------------------------------
// A -> A2m scan A-frags, wave-per-(ib, chunk). Lanes load A in frag order
// (8 guarded dwords; odd row stride forbids float4), store coalesced dwordx4.
__global__ __launch_bounds__(256) void k_tr(const float* __restrict__ A,
                                            unsigned short* __restrict__ A2m) {
    const int tid = threadIdx.x;
    const int lane = tid & 63, w = tid >> 6;
    const int task = blockIdx.x * 4 + w;          // < 289*152 = 43,928
    const int ib = task / NKC, m = task - ib * NKC;
    const int r = lane & 15, g = lane >> 4;
    const int row = ib * 16 + r;
    const int c0 = m * 32 + g * 8;

    float f[8];
    if (row < N_TH && c0 + 7 < N_TH) {
        const float* ap = A + (size_t)row * N_TH + c0;
#pragma unroll
        for (int e = 0; e < 8; e++) f[e] = ap[e];
    } else {
#pragma unroll
        for (int e = 0; e < 8; e++) {
            int c = c0 + e;
            f[e] = (row < N_TH && c < N_TH) ? A[(size_t)row * N_TH + c] : 0.f;
        }
    }
#pragma unroll
    for (int e = 0; e < 8; e++)
        if (row == c0 + e) f[e] -= 1.f;           // E = A - I

    uint4 o;
    o.x = (unsigned int)f2bf(f[0]) | ((unsigned int)f2bf(f[1]) << 16);
    o.y = (unsigned int)f2bf(f[2]) | ((unsigned int)f2bf(f[3]) << 16);
    o.z = (unsigned int)f2bf(f[4]) | ((unsigned int)f2bf(f[5]) << 16);
    o.w = (unsigned int)f2bf(f[6]) | ((unsigned int)f2bf(f[7]) << 16);
    ((uint4*)A2m)[(size_t)task * 64 + lane] = o;
}

// ---------------------------------------------------------------------------
// One scan step: grid (289, 2). Unit u = q*4+w owns exactly 19 chunks.
// Cross-block combine via fp32 atomicAdd into Prow (2 adds, commutative ->
// deterministic) + arrival counter; winner does the epilogue.
__global__ __launch_bounds__(256) void k_step(const bfrag8* __restrict__ A2m,
                                              const bfrag8* __restrict__ Bsrc,
                                              unsigned short* __restrict__ Pdst,
                                              float* __restrict__ Prow,
                                              float* __restrict__ PcolB,
                                              unsigned short* __restrict__ PmcH,
                                              unsigned short* __restrict__ PmcL,
                                              int* __restrict__ cnt,
                                              int k) {
    __shared__ float red[4][256];
    __shared__ int sflag;
    const int tid = threadIdx.x, lane = tid & 63, w = tid >> 6;
    const int ib = blockIdx.x, q = blockIdx.y;
    const int cs = (q * 4 + w) * 19;
    const size_t ab = ((size_t)ib * NKC + cs) * 64 + lane;
    const size_t bb = (size_t)cs * 64 + lane;

    bfrag8 ra[4], rb[4];
#pragma unroll
    for (int u = 0; u < 4; u++) {
        ra[u] = A2m[ab + (size_t)u * 64];
        rb[u] = Bsrc[bb + (size_t)u * 64];
    }
    f32x4 acc = {0.f, 0.f, 0.f, 0.f};
#pragma unroll
    for (int ch = 0; ch < 19; ch++) {
        acc = __builtin_amdgcn_mfma_f32_16x16x32_bf16(ra[ch & 3], rb[ch & 3], acc, 0, 0, 0);
        if (ch + 4 < 19) {
            ra[ch & 3] = A2m[ab + (size_t)(ch + 4) * 64];
            rb[ch & 3] = Bsrc[bb + (size_t)(ch + 4) * 64];
        }
    }

    // C/D layout: col=lane&15, row=(lane>>4)*4+reg  [verified R7]
#pragma unroll
    for (int r = 0; r < 4; r++)
        red[w][(((lane >> 4) * 4) + r) * 16 + (lane & 15)] = acc[r];
    __syncthreads();

    float s = red[0][tid] + red[1][tid] + red[2][tid] + red[3][tid];
    const int row = tid >> 4, c = tid & 15;
    const int i = ib * 16 + row;
    const bool valid = (i < N_TH) && (c < 11);
    if (valid) atomicAdd(&Prow[i * 12 + c], s);
    __threadfence();
    __syncthreads();
    if (tid == 0) sflag = (atomicAdd(&cnt[ib], 1) == 1);
    __syncthreads();
    if (sflag) {
        if (tid == 0) cnt[ib] = 0;                 // reset for next step
        if (valid) {
            float pnew = atomicAdd(&Prow[i * 12 + c], 0.0f);   // coherent read
            if (c == 0) {
                PcolB[(size_t)(k - 1) * 4624 + i] = pnew;      // bias plane t=k-1
            } else if (k <= 31) {
                int kidx = k * 10 + (c - 1);
                int kc = kidx >> 5, kr = kidx & 31;
                size_t slot = ((size_t)(kc * NIB + (i >> 4)) << 9) +
                              (size_t)(((kr >> 3) * 16 + (i & 15)) << 3) + (kr & 7);
                unsigned short h = f2bf(pnew);
                PmcH[slot] = h;
                PmcL[slot] = f2bf(pnew - bf2f(h));
            }
            if (k <= 31) {
                int ch2 = i >> 5, kr2 = i & 31;
                Pdst[(size_t)ch2 * 512 +
                     (size_t)(((kr2 >> 3) * 16 + c) << 3) + (kr2 & 7)] = f2bf(pnew);
            }
        }
    }
}

// ---------------------------------------------------------------------------
// conv GEMM via MFMA, split precision (hh + hl + lh): M=1024, N=4609, K=320.
// grid (37, 16): block = 8 ic-tiles x 4 mt (4 waves); wave owns mt, 8 acc tiles.
__global__ __launch_bounds__(256) void k_conv(const bfrag8* __restrict__ CfH,
                                              const bfrag8* __restrict__ CfL,
                                              const bfrag8* __restrict__ PmcH,
                                              const bfrag8* __restrict__ PmcL,
                                              const float* __restrict__ PcolB,
                                              float* __restrict__ theta) {
    const int tid = threadIdx.x, lane = tid & 63, w = tid >> 6;
    const int icg = blockIdx.x;
    const int mt  = blockIdx.y * 4 + w;
    const int icmax = NIB - icg * 8;    // valid ic tiles in this block (>=1)

    f32x4 acc[8];
#pragma unroll
    for (int t8 = 0; t8 < 8; t8++) acc[t8] = (f32x4){0.f, 0.f, 0.f, 0.f};

#pragma unroll 1
    for (int kc = 0; kc < 10; kc++) {
        bfrag8 ah = CfH[(size_t)(kc * 64 + mt) * 64 + lane];
        bfrag8 al = CfL[(size_t)(kc * 64 + mt) * 64 + lane];
#pragma unroll
        for (int t8 = 0; t8 < 8; t8++) {
            if (t8 < icmax) {
                size_t bo = (size_t)(kc * NIB + icg * 8 + t8) * 64 + lane;
                bfrag8 bh = PmcH[bo];
                bfrag8 bl = PmcL[bo];
                acc[t8] = __builtin_amdgcn_mfma_f32_16x16x32_bf16(ah, bh, acc[t8], 0, 0, 0);
                acc[t8] = __builtin_amdgcn_mfma_f32_16x16x32_bf16(ah, bl, acc[t8], 0, 0, 0);
                acc[t8] = __builtin_amdgcn_mfma_f32_16x16x32_bf16(al, bh, acc[t8], 0, 0, 0);
            }
        }
    }

    const int n = lane & 15, gg = lane >> 4;
#pragma unroll
    for (int t8 = 0; t8 < 8; t8++) {
        if (t8 < icmax) {
            int i = (icg * 8 + t8) * 16 + n;
            if (i < N_TH) {
#pragma unroll
                for (int r = 0; r < 4; r++) {
                    int bt = mt * 16 + gg * 4 + r;
                    int t = bt & 31;
                    theta[(size_t)bt * TSTR + i] = acc[t8][r] + PcolB[(size_t)t * 4624 + i];
                }
            }
        }
    }
}

// ---------------------------------------------------------------------------
__global__ __launch_bounds__(256) void k_mlp(const float* __restrict__ xs,
                                             const float* __restrict__ ts,
                                             const float* __restrict__ theta,
                                             float* __restrict__ out) {
    const int tid  = threadIdx.x;
    const int lane = tid & 63;
    const int half = (lane >> 5) & 1;
    const int o    = lane & 31;
    const int wv   = tid >> 6;
    const int bt   = blockIdx.x * 8 + wv * 2 + half;
    const int b = bt >> 5, t = bt & 31;
    const float* th = theta + (size_t)bt * TSTR;

    float u[10];
    u[0] = ts[b * NL + t];
#pragma unroll
    for (int d = 0; d < 9; d++) u[1 + d] = xs[(b * NL + t) * 9 + d];

    float acc = th[320 + o];
#pragma unroll
    for (int i = 0; i < 10; i++) acc = fmaf(th[o * 10 + i], u[i], acc);
    float h = fmaxf(acc, 0.f);

#pragma unroll
    for (int l = 0; l < 4; l++) {
        int base = 352 + l * 1056;
        float a2 = th[base + 1024 + o];
#pragma unroll
        for (int i = 0; i < 32; i++)
            a2 = fmaf(th[base + o * 32 + i], __shfl(h, i, 32), a2);
        h = fmaxf(a2, 0.f);
    }

    float contrib = th[4576 + o] * h;
#pragma unroll
    for (int m = 16; m >= 1; m >>= 1) contrib += __shfl_xor(contrib, m, 32);
    if (o == 0) out[bt] = contrib + th[4608];
}

// ---------------------------------------------------------------------------
extern "C" void kernel_launch(void* const* d_in, const int* in_sizes, int n_in,
                              void* d_out, int out_size, void* d_ws, size_t ws_size,
                              hipStream_t stream) {
    const float* xs  = (const float*)d_in[0];
    const float* ts  = (const float*)d_in[1];
    const float* A   = (const float*)d_in[2];
    const float* Bm  = (const float*)d_in[3];
    const float* th0 = (const float*)d_in[4];
    float* out = (float*)d_out;
    float* ws  = (float*)d_ws;

    float*          Prow  = ws + OF_PROW;
    unsigned short* Pmf   = (unsigned short*)(ws + OF_PMF);
    int*            cnt   = (int*)(ws + OF_CNT);
    float*          PcolB = ws + OF_PCOLB;
    unsigned short* PmcH  = (unsigned short*)(ws + OF_PMCH);
    unsigned short* PmcL  = (unsigned short*)(ws + OF_PMCL);
    unsigned short* CfH   = (unsigned short*)(ws + OF_CFH);
    unsigned short* CfL   = (unsigned short*)(ws + OF_CFL);
    unsigned short* A2m   = (unsigned short*)(ws + OF_A2M);
    float*          theta = ws + OF_A2M;   // aliases A2m (dead after scan)

    k_p0<<<304, 256, 0, stream>>>(th0, Bm, Prow, Pmf, PmcH, PmcL, cnt);
    k_cf<<<1280, 256, 0, stream>>>(xs, ts, CfH, CfL);
    k_tr<<<10982, 256, 0, stream>>>(A, A2m);

    for (int k = 1; k <= 32; k++) {
        const unsigned short* src = Pmf + (size_t)((k - 1) & 1) * (NKC * 512);
        unsigned short* dst       = Pmf + (size_t)(k & 1) * (NKC * 512);
        k_step<<<dim3(NIB, 2), 256, 0, stream>>>((const bfrag8*)A2m, (const bfrag8*)src,
                                                 dst, Prow, PcolB, PmcH, PmcL, cnt, k);
    }

    k_conv<<<dim3(37, 16), 256, 0, stream>>>((const bfrag8*)CfH, (const bfrag8*)CfL,
                                             (const bfrag8*)PmcH, (const bfrag8*)PmcL,
                                             PcolB, theta);
    k_mlp<<<128, 256, 0, stream>>>(xs, ts, theta, out);
}

// Round 9
// 433.705 us; speedup vs baseline: 4.7594x; 4.7594x over previous
//
#include <hip/hip_runtime.h>

typedef __attribute__((ext_vector_type(8))) short bfrag8;   // 8 bf16 (4 VGPR)
typedef __attribute__((ext_vector_type(4))) float f32x4;    // MFMA acc

// Problem constants
#define N_TH   4609      // D_THETA
#define NIB    289       // i-blocks of 16 (289*16 = 4624)
#define NKC    152       // j-chunks of 32 (8*19; chunks >=145 are zero pad)
#define TSTR   4612      // theta row stride (floats)
#define NB     32
#define NL     32

// ws layout (float offsets); total 13,482,176 fl = 53.93 MB (< proven 55.02 MB)
#define OF_PROW  0          // 4624*12 = 55,488
#define OF_PMF   55488      // 2 x 152*512 ushort = 77,824 fl
#define OF_PART  133312     // 2*289*256 = 147,968 fl
#define OF_PCOLB 281280     // 32*4624 = 147,968
#define OF_PMCH  429248     // 10*289*512 ushort = 739,840 fl
#define OF_PMCL  1169088    // 739,840 fl
#define OF_CFH   1908928    // 10*64*512 ushort = 163,840 fl
#define OF_CFL   2072768    // 163,840 fl
#define OF_A2M   2236608    // 289*152*512 ushort = 11,245,568 fl ; theta aliases

__device__ __forceinline__ unsigned short f2bf(float v) {
    unsigned int u = __float_as_uint(v);
    return (unsigned short)((u + 0x7fffu + ((u >> 16) & 1u)) >> 16);  // RNE
}
__device__ __forceinline__ float bf2f(unsigned short h) {
    return __uint_as_float((unsigned int)h << 16);
}

// ---------------------------------------------------------------------------
// P_0: Prow fp32, scan B-frags (Pmf buf0; buf1 zeroed), conv B-frags plane j=0.
// idx over 152*32*16 = 77,824.
__global__ __launch_bounds__(256) void k_p0(const float* __restrict__ th0,
                                            const float* __restrict__ Bm,
                                            float* __restrict__ Prow,
                                            unsigned short* __restrict__ Pmf,
                                            unsigned short* __restrict__ PmcH,
                                            unsigned short* __restrict__ PmcL) {
    int idx = blockIdx.x * 256 + threadIdx.x;
    if (idx >= NKC * 32 * 16) return;
    int i = idx >> 4, c = idx & 15;
    float v = 0.f;
    if (i < N_TH && c < 11) {
        if (c == 0) v = th0[i];
        else v = Bm[(size_t)i * 10 + (c - 1)];
    }
    if (i < 4624 && c < 12) Prow[i * 12 + c] = v;
    // scan B-frag slot
    int ch = i >> 5, kr = i & 31;
    size_t slot = (size_t)ch * 512 + (size_t)(((kr >> 3) * 16 + c) << 3) + (kr & 7);
    Pmf[slot] = (v == 0.f) ? (unsigned short)0 : f2bf(v);
    Pmf[(size_t)NKC * 512 + slot] = 0;
    // conv B-frag plane j=0 (kidx = c-1, kc=0)
    if (c >= 1 && c <= 10 && i < N_TH) {
        int kidx = c - 1;
        size_t s2 = ((size_t)(i >> 4) << 9) +
                    (size_t)((((kidx & 31) >> 3) * 16 + (i & 15)) << 3) + (kidx & 7);
        unsigned short h = f2bf(v);
        PmcH[s2] = h;
        PmcL[s2] = f2bf(v - bf2f(h));
    }
}

// ---------------------------------------------------------------------------
// du-coef -> conv A-frags (hi/lo), computed directly from xs/ts.
__global__ __launch_bounds__(256) void k_cf(const float* __restrict__ xs,
                                            const float* __restrict__ ts,
                                            unsigned short* __restrict__ CfH,
                                            unsigned short* __restrict__ CfL) {
    int idx = blockIdx.x * 256 + threadIdx.x;
    if (idx >= 10 * 64 * 512) return;
    int kk = idx & 7;
    int l  = (idx >> 3) & 63;
    int mt = (idx >> 9) & 63;
    int kc = idx >> 15;
    int bt = mt * 16 + (l & 15);
    int t = bt & 31, b = bt >> 5;
    int kidx = kc * 32 + (l >> 4) * 8 + kk;
    int j = kidx / 10, d = kidx - j * 10;
    float v = 0.f;
    if (j < t) {
        int tt = t - j;   // >= 1
        v = (d == 0) ? (ts[b * NL + tt] - ts[b * NL + tt - 1])
                     : (xs[(size_t)(b * NL + tt) * 9 + d - 1] -
                        xs[(size_t)(b * NL + tt - 1) * 9 + d - 1]);
    }
    unsigned short h = f2bf(v);
    CfH[idx] = h;
    CfL[idx] = f2bf(v - bf2f(h));
}

// ---------------------------------------------------------------------------
// A -> A2m scan A-frags, wave-per-(ib, chunk); coalesced dwordx4 stores.
__global__ __launch_bounds__(256) void k_tr(const float* __restrict__ A,
                                            unsigned short* __restrict__ A2m) {
    const int tid = threadIdx.x;
    const int lane = tid & 63, w = tid >> 6;
    const int task = blockIdx.x * 4 + w;          // < 289*152 = 43,928
    const int ib = task / NKC, m = task - ib * NKC;
    const int r = lane & 15, g = lane >> 4;
    const int row = ib * 16 + r;
    const int c0 = m * 32 + g * 8;

    float f[8];
    if (row < N_TH && c0 + 7 < N_TH) {
        const float* ap = A + (size_t)row * N_TH + c0;
#pragma unroll
        for (int e = 0; e < 8; e++) f[e] = ap[e];
    } else {
#pragma unroll
        for (int e = 0; e < 8; e++) {
            int c = c0 + e;
            f[e] = (row < N_TH && c < N_TH) ? A[(size_t)row * N_TH + c] : 0.f;
        }
    }
#pragma unroll
    for (int e = 0; e < 8; e++)
        if (row == c0 + e) f[e] -= 1.f;           // E = A - I

    uint4 o;
    o.x = (unsigned int)f2bf(f[0]) | ((unsigned int)f2bf(f[1]) << 16);
    o.y = (unsigned int)f2bf(f[2]) | ((unsigned int)f2bf(f[3]) << 16);
    o.z = (unsigned int)f2bf(f[4]) | ((unsigned int)f2bf(f[5]) << 16);
    o.w = (unsigned int)f2bf(f[6]) | ((unsigned int)f2bf(f[7]) << 16);
    ((uint4*)A2m)[(size_t)task * 64 + lane] = o;
}

// ---------------------------------------------------------------------------
// Scan step, split-K: grid (289, 2). Unit u = q*4+w owns exactly 19 chunks.
// Block-local LDS reduce; plain store of one 256-fl partial slice. No atomics.
__global__ __launch_bounds__(256) void k_stepK(const bfrag8* __restrict__ A2m,
                                               const bfrag8* __restrict__ Bsrc,
                                               float* __restrict__ part) {
    __shared__ float red[4][256];
    const int tid = threadIdx.x, lane = tid & 63, w = tid >> 6;
    const int ib = blockIdx.x, q = blockIdx.y;
    const int cs = (q * 4 + w) * 19;
    const size_t ab = ((size_t)ib * NKC + cs) * 64 + lane;
    const size_t bb = (size_t)cs * 64 + lane;

    bfrag8 ra[4], rb[4];
#pragma unroll
    for (int u = 0; u < 4; u++) {
        ra[u] = A2m[ab + (size_t)u * 64];
        rb[u] = Bsrc[bb + (size_t)u * 64];
    }
    f32x4 acc = {0.f, 0.f, 0.f, 0.f};
#pragma unroll
    for (int ch = 0; ch < 19; ch++) {
        acc = __builtin_amdgcn_mfma_f32_16x16x32_bf16(ra[ch & 3], rb[ch & 3], acc, 0, 0, 0);
        if (ch + 4 < 19) {
            ra[ch & 3] = A2m[ab + (size_t)(ch + 4) * 64];
            rb[ch & 3] = Bsrc[bb + (size_t)(ch + 4) * 64];
        }
    }

    // C/D layout: col=lane&15, row=(lane>>4)*4+reg  [verified R7]
#pragma unroll
    for (int r = 0; r < 4; r++)
        red[w][(((lane >> 4) * 4) + r) * 16 + (lane & 15)] = acc[r];
    __syncthreads();

    float s = red[0][tid] + red[1][tid] + red[2][tid] + red[3][tid];
    part[(size_t)(q * NIB + ib) * 256 + tid] = s;
}

// ---------------------------------------------------------------------------
// Finalize step k: P_k = P_{k-1} + part0 + part1 -> Prow, bias plane (c==0),
// conv frags (c 1..10, k<=31), next scan B-frags (k<=31). grid 289.
__global__ __launch_bounds__(256) void k_fin(const float* __restrict__ part,
                                             float* __restrict__ Prow,
                                             float* __restrict__ PcolB,
                                             unsigned short* __restrict__ PmcH,
                                             unsigned short* __restrict__ PmcL,
                                             unsigned short* __restrict__ Pdst,
                                             int k) {
    const int tid = threadIdx.x;
    const int ib = blockIdx.x;
    const int row = tid >> 4, c = tid & 15;
    const int i = ib * 16 + row;
    if (i >= N_TH || c >= 11) return;
    float s = part[(size_t)ib * 256 + tid] + part[(size_t)(NIB + ib) * 256 + tid];
    float pnew = Prow[i * 12 + c] + s;
    Prow[i * 12 + c] = pnew;
    if (c == 0) {
        PcolB[(size_t)(k - 1) * 4624 + i] = pnew;      // bias plane t=k-1
    } else if (k <= 31) {
        int kidx = k * 10 + (c - 1);
        int kc = kidx >> 5, kr = kidx & 31;
        size_t slot = ((size_t)(kc * NIB + (i >> 4)) << 9) +
                      (size_t)(((kr >> 3) * 16 + (i & 15)) << 3) + (kr & 7);
        unsigned short h = f2bf(pnew);
        PmcH[slot] = h;
        PmcL[slot] = f2bf(pnew - bf2f(h));
    }
    if (k <= 31) {
        int ch2 = i >> 5, kr2 = i & 31;
        Pdst[(size_t)ch2 * 512 +
             (size_t)(((kr2 >> 3) * 16 + c) << 3) + (kr2 & 7)] = f2bf(pnew);
    }
}

// ---------------------------------------------------------------------------
// conv GEMM via MFMA, split precision (hh + hl + lh): M=1024, N=4609, K=320.
// grid (37, 16): wave owns mt, 8 ic-tile accumulators.
__global__ __launch_bounds__(256) void k_conv(const bfrag8* __restrict__ CfH,
                                              const bfrag8* __restrict__ CfL,
                                              const bfrag8* __restrict__ PmcH,
                                              const bfrag8* __restrict__ PmcL,
                                              const float* __restrict__ PcolB,
                                              float* __restrict__ theta) {
    const int tid = threadIdx.x, lane = tid & 63, w = tid >> 6;
    const int icg = blockIdx.x;
    const int mt  = blockIdx.y * 4 + w;
    const int icmax = NIB - icg * 8;    // valid ic tiles in this block (>=1)

    f32x4 acc[8];
#pragma unroll
    for (int t8 = 0; t8 < 8; t8++) acc[t8] = (f32x4){0.f, 0.f, 0.f, 0.f};

#pragma unroll 1
    for (int kc = 0; kc < 10; kc++) {
        bfrag8 ah = CfH[(size_t)(kc * 64 + mt) * 64 + lane];
        bfrag8 al = CfL[(size_t)(kc * 64 + mt) * 64 + lane];
#pragma unroll
        for (int t8 = 0; t8 < 8; t8++) {
            if (t8 < icmax) {
                size_t bo = (size_t)(kc * NIB + icg * 8 + t8) * 64 + lane;
                bfrag8 bh = PmcH[bo];
                bfrag8 bl = PmcL[bo];
                acc[t8] = __builtin_amdgcn_mfma_f32_16x16x32_bf16(ah, bh, acc[t8], 0, 0, 0);
                acc[t8] = __builtin_amdgcn_mfma_f32_16x16x32_bf16(ah, bl, acc[t8], 0, 0, 0);
                acc[t8] = __builtin_amdgcn_mfma_f32_16x16x32_bf16(al, bh, acc[t8], 0, 0, 0);
            }
        }
    }

    const int n = lane & 15, gg = lane >> 4;
#pragma unroll
    for (int t8 = 0; t8 < 8; t8++) {
        if (t8 < icmax) {
            int i = (icg * 8 + t8) * 16 + n;
            if (i < N_TH) {
#pragma unroll
                for (int r = 0; r < 4; r++) {
                    int bt = mt * 16 + gg * 4 + r;
                    int t = bt & 31;
                    theta[(size_t)bt * TSTR + i] = acc[t8][r] + PcolB[(size_t)t * 4624 + i];
                }
            }
        }
    }
}

// ---------------------------------------------------------------------------
__global__ __launch_bounds__(256) void k_mlp(const float* __restrict__ xs,
                                             const float* __restrict__ ts,
                                             const float* __restrict__ theta,
                                             float* __restrict__ out) {
    const int tid  = threadIdx.x;
    const int lane = tid & 63;
    const int half = (lane >> 5) & 1;
    const int o    = lane & 31;
    const int wv   = tid >> 6;
    const int bt   = blockIdx.x * 8 + wv * 2 + half;
    const int b = bt >> 5, t = bt & 31;
    const float* th = theta + (size_t)bt * TSTR;

    float u[10];
    u[0] = ts[b * NL + t];
#pragma unroll
    for (int d = 0; d < 9; d++) u[1 + d] = xs[(b * NL + t) * 9 + d];

    float acc = th[320 + o];
#pragma unroll
    for (int i = 0; i < 10; i++) acc = fmaf(th[o * 10 + i], u[i], acc);
    float h = fmaxf(acc, 0.f);

#pragma unroll
    for (int l = 0; l < 4; l++) {
        int base = 352 + l * 1056;
        float a2 = th[base + 1024 + o];
#pragma unroll
        for (int i = 0; i < 32; i++)
            a2 = fmaf(th[base + o * 32 + i], __shfl(h, i, 32), a2);
        h = fmaxf(a2, 0.f);
    }

    float contrib = th[4576 + o] * h;
#pragma unroll
    for (int m = 16; m >= 1; m >>= 1) contrib += __shfl_xor(contrib, m, 32);
    if (o == 0) out[bt] = contrib + th[4608];
}

// ---------------------------------------------------------------------------
extern "C" void kernel_launch(void* const* d_in, const int* in_sizes, int n_in,
                              void* d_out, int out_size, void* d_ws, size_t ws_size,
                              hipStream_t stream) {
    const float* xs  = (const float*)d_in[0];
    const float* ts  = (const float*)d_in[1];
    const float* A   = (const float*)d_in[2];
    const float* Bm  = (const float*)d_in[3];
    const float* th0 = (const float*)d_in[4];
    float* out = (float*)d_out;
    float* ws  = (float*)d_ws;

    float*          Prow  = ws + OF_PROW;
    unsigned short* Pmf   = (unsigned short*)(ws + OF_PMF);
    float*          part  = ws + OF_PART;
    float*          PcolB = ws + OF_PCOLB;
    unsigned short* PmcH  = (unsigned short*)(ws + OF_PMCH);
    unsigned short* PmcL  = (unsigned short*)(ws + OF_PMCL);
    unsigned short* CfH   = (unsigned short*)(ws + OF_CFH);
    unsigned short* CfL   = (unsigned short*)(ws + OF_CFL);
    unsigned short* A2m   = (unsigned short*)(ws + OF_A2M);
    float*          theta = ws + OF_A2M;   // aliases A2m (dead after scan)

    k_p0<<<304, 256, 0, stream>>>(th0, Bm, Prow, Pmf, PmcH, PmcL);
    k_cf<<<1280, 256, 0, stream>>>(xs, ts, CfH, CfL);
    k_tr<<<10982, 256, 0, stream>>>(A, A2m);

    for (int k = 1; k <= 32; k++) {
        const unsigned short* src = Pmf + (size_t)((k - 1) & 1) * (NKC * 512);
        unsigned short* dst       = Pmf + (size_t)(k & 1) * (NKC * 512);
        k_stepK<<<dim3(NIB, 2), 256, 0, stream>>>((const bfrag8*)A2m, (const bfrag8*)src, part);
        k_fin<<<NIB, 256, 0, stream>>>(part, Prow, PcolB, PmcH, PmcL, dst, k);
    }

    k_conv<<<dim3(37, 16), 256, 0, stream>>>((const bfrag8*)CfH, (const bfrag8*)CfL,
                                             (const bfrag8*)PmcH, (const bfrag8*)PmcL,
                                             PcolB, theta);
    k_mlp<<<128, 256, 0, stream>>>(xs, ts, theta, out);
}

// Round 10
// 418.384 us; speedup vs baseline: 4.9337x; 1.0366x over previous
//
#include <hip/hip_runtime.h>

typedef __attribute__((ext_vector_type(8))) short bfrag8;   // 8 bf16 (4 VGPR)
typedef __attribute__((ext_vector_type(4))) float f32x4;    // MFMA acc

// Problem constants
#define N_TH   4609      // D_THETA
#define NIB    289       // i-blocks of 16 (289*16 = 4624)
#define NKC    152       // j-chunks of 32 (chunks >=145 are zero pad)
#define TSTR   4612      // theta row stride (floats)
#define NB     32
#define NL     32

// ws layout (float offsets); total 13,630,144 fl = 54.52 MB (< proven 55.03 MB)
#define OF_PROW  0          // 4624*12 = 55,488
#define OF_PMF   55488      // 2 x 152*512 ushort = 77,824 fl
#define OF_PART  133312     // 4*289*256 = 295,936 fl
#define OF_PCOLB 429248     // 32*4624 = 147,968
#define OF_PMCH  577216     // 10*289*512 ushort = 739,840 fl
#define OF_PMCL  1317056    // 739,840 fl
#define OF_CFH   2056896    // 10*64*512 ushort = 163,840 fl
#define OF_CFL   2220736    // 163,840 fl
#define OF_A2M   2384576    // 289*152*512 ushort = 11,245,568 fl ; theta aliases

__device__ __forceinline__ unsigned short f2bf(float v) {
    unsigned int u = __float_as_uint(v);
    return (unsigned short)((u + 0x7fffu + ((u >> 16) & 1u)) >> 16);  // RNE
}
__device__ __forceinline__ float bf2f(unsigned short h) {
    return __uint_as_float((unsigned int)h << 16);
}

// ---------------------------------------------------------------------------
// P_0: Prow fp32, scan B-frags (Pmf buf0; buf1 zeroed), conv B-frags plane j=0.
__global__ __launch_bounds__(256) void k_p0(const float* __restrict__ th0,
                                            const float* __restrict__ Bm,
                                            float* __restrict__ Prow,
                                            unsigned short* __restrict__ Pmf,
                                            unsigned short* __restrict__ PmcH,
                                            unsigned short* __restrict__ PmcL) {
    int idx = blockIdx.x * 256 + threadIdx.x;
    if (idx >= NKC * 32 * 16) return;
    int i = idx >> 4, c = idx & 15;
    float v = 0.f;
    if (i < N_TH && c < 11) {
        if (c == 0) v = th0[i];
        else v = Bm[(size_t)i * 10 + (c - 1)];
    }
    if (i < 4624 && c < 12) Prow[i * 12 + c] = v;
    // scan B-frag slot
    int ch = i >> 5, kr = i & 31;
    size_t slot = (size_t)ch * 512 + (size_t)(((kr >> 3) * 16 + c) << 3) + (kr & 7);
    Pmf[slot] = (v == 0.f) ? (unsigned short)0 : f2bf(v);
    Pmf[(size_t)NKC * 512 + slot] = 0;
    // conv B-frag plane j=0 (kidx = c-1, kc=0)
    if (c >= 1 && c <= 10 && i < N_TH) {
        int kidx = c - 1;
        size_t s2 = ((size_t)(i >> 4) << 9) +
                    (size_t)((((kidx & 31) >> 3) * 16 + (i & 15)) << 3) + (kidx & 7);
        unsigned short h = f2bf(v);
        PmcH[s2] = h;
        PmcL[s2] = f2bf(v - bf2f(h));
    }
}

// ---------------------------------------------------------------------------
// du-coef -> conv A-frags (hi/lo), computed directly from xs/ts.
__global__ __launch_bounds__(256) void k_cf(const float* __restrict__ xs,
                                            const float* __restrict__ ts,
                                            unsigned short* __restrict__ CfH,
                                            unsigned short* __restrict__ CfL) {
    int idx = blockIdx.x * 256 + threadIdx.x;
    if (idx >= 10 * 64 * 512) return;
    int kk = idx & 7;
    int l  = (idx >> 3) & 63;
    int mt = (idx >> 9) & 63;
    int kc = idx >> 15;
    int bt = mt * 16 + (l & 15);
    int t = bt & 31, b = bt >> 5;
    int kidx = kc * 32 + (l >> 4) * 8 + kk;
    int j = kidx / 10, d = kidx - j * 10;
    float v = 0.f;
    if (j < t) {
        int tt = t - j;   // >= 1
        v = (d == 0) ? (ts[b * NL + tt] - ts[b * NL + tt - 1])
                     : (xs[(size_t)(b * NL + tt) * 9 + d - 1] -
                        xs[(size_t)(b * NL + tt - 1) * 9 + d - 1]);
    }
    unsigned short h = f2bf(v);
    CfH[idx] = h;
    CfL[idx] = f2bf(v - bf2f(h));
}

// ---------------------------------------------------------------------------
// A -> A2m scan A-frags, wave-per-(ib, chunk); coalesced dwordx4 stores.
__global__ __launch_bounds__(256) void k_tr(const float* __restrict__ A,
                                            unsigned short* __restrict__ A2m) {
    const int tid = threadIdx.x;
    const int lane = tid & 63, w = tid >> 6;
    const int task = blockIdx.x * 4 + w;          // < 289*152 = 43,928
    const int ib = task / NKC, m = task - ib * NKC;
    const int r = lane & 15, g = lane >> 4;
    const int row = ib * 16 + r;
    const int c0 = m * 32 + g * 8;

    float f[8];
    if (row < N_TH && c0 + 7 < N_TH) {
        const float* ap = A + (size_t)row * N_TH + c0;
#pragma unroll
        for (int e = 0; e < 8; e++) f[e] = ap[e];
    } else {
#pragma unroll
        for (int e = 0; e < 8; e++) {
            int c = c0 + e;
            f[e] = (row < N_TH && c < N_TH) ? A[(size_t)row * N_TH + c] : 0.f;
        }
    }
#pragma unroll
    for (int e = 0; e < 8; e++)
        if (row == c0 + e) f[e] -= 1.f;           // E = A - I

    uint4 o;
    o.x = (unsigned int)f2bf(f[0]) | ((unsigned int)f2bf(f[1]) << 16);
    o.y = (unsigned int)f2bf(f[2]) | ((unsigned int)f2bf(f[3]) << 16);
    o.z = (unsigned int)f2bf(f[4]) | ((unsigned int)f2bf(f[5]) << 16);
    o.w = (unsigned int)f2bf(f[6]) | ((unsigned int)f2bf(f[7]) << 16);
    ((uint4*)A2m)[(size_t)task * 64 + lane] = o;
}

// ---------------------------------------------------------------------------
// MFMA run over NCH chunks with a depth-5 register ring (>=10 loads in flight).
template<int NCH>
__device__ __forceinline__ f32x4 mfma_run(const bfrag8* __restrict__ ap,
                                          const bfrag8* __restrict__ bp) {
    bfrag8 ra[5], rb[5];
#pragma unroll
    for (int c = 0; c < 5; c++) {
        ra[c] = ap[(size_t)c * 64];
        rb[c] = bp[(size_t)c * 64];
    }
    f32x4 acc = {0.f, 0.f, 0.f, 0.f};
#pragma unroll
    for (int c = 0; c < NCH; c++) {
        acc = __builtin_amdgcn_mfma_f32_16x16x32_bf16(ra[c % 5], rb[c % 5], acc, 0, 0, 0);
        if (c + 5 < NCH) {
            ra[c % 5] = ap[(size_t)(c + 5) * 64];
            rb[c % 5] = bp[(size_t)(c + 5) * 64];
        }
    }
    return acc;
}

// ---------------------------------------------------------------------------
// Scan step, split-K 4 ways: grid (289, 4). Wave-unit u = q*4+w owns 10 chunks
// (u<8) or 9 chunks (u>=8): 8*10+8*9 = 152. Block-local LDS reduce; plain
// store of one 256-fl partial slice. No atomics, no fences.
__global__ __launch_bounds__(256) void k_stepK(const bfrag8* __restrict__ A2m,
                                               const bfrag8* __restrict__ Bsrc,
                                               float* __restrict__ part) {
    __shared__ float red[4][256];
    const int tid = threadIdx.x, lane = tid & 63, w = tid >> 6;
    const int ib = blockIdx.x, q = blockIdx.y;
    const int u = q * 4 + w;
    const int cs = (u < 8) ? u * 10 : 80 + (u - 8) * 9;
    const bfrag8* ap = A2m + ((size_t)ib * NKC + cs) * 64 + lane;
    const bfrag8* bp = Bsrc + (size_t)cs * 64 + lane;

    f32x4 acc = (u < 8) ? mfma_run<10>(ap, bp) : mfma_run<9>(ap, bp);

    // C/D layout: col=lane&15, row=(lane>>4)*4+reg  [verified R7]
#pragma unroll
    for (int r = 0; r < 4; r++)
        red[w][(((lane >> 4) * 4) + r) * 16 + (lane & 15)] = acc[r];
    __syncthreads();

    float s = red[0][tid] + red[1][tid] + red[2][tid] + red[3][tid];
    part[(size_t)(q * NIB + ib) * 256 + tid] = s;
}

// ---------------------------------------------------------------------------
// Finalize step k: P_k = P_{k-1} + sum of 4 partial slices -> Prow, bias plane
// (c==0), conv frags (c 1..10, k<=31), next scan B-frags (k<=31). grid 289.
__global__ __launch_bounds__(256) void k_fin(const float* __restrict__ part,
                                             float* __restrict__ Prow,
                                             float* __restrict__ PcolB,
                                             unsigned short* __restrict__ PmcH,
                                             unsigned short* __restrict__ PmcL,
                                             unsigned short* __restrict__ Pdst,
                                             int k) {
    const int tid = threadIdx.x;
    const int ib = blockIdx.x;
    const int row = tid >> 4, c = tid & 15;
    const int i = ib * 16 + row;
    if (i >= N_TH || c >= 11) return;
    float s = part[(size_t)ib * 256 + tid]
            + part[(size_t)(NIB + ib) * 256 + tid]
            + part[(size_t)(2 * NIB + ib) * 256 + tid]
            + part[(size_t)(3 * NIB + ib) * 256 + tid];
    float pnew = Prow[i * 12 + c] + s;
    Prow[i * 12 + c] = pnew;
    if (c == 0) {
        PcolB[(size_t)(k - 1) * 4624 + i] = pnew;      // bias plane t=k-1
    } else if (k <= 31) {
        int kidx = k * 10 + (c - 1);
        int kc = kidx >> 5, kr = kidx & 31;
        size_t slot = ((size_t)(kc * NIB + (i >> 4)) << 9) +
                      (size_t)(((kr >> 3) * 16 + (i & 15)) << 3) + (kr & 7);
        unsigned short h = f2bf(pnew);
        PmcH[slot] = h;
        PmcL[slot] = f2bf(pnew - bf2f(h));
    }
    if (k <= 31) {
        int ch2 = i >> 5, kr2 = i & 31;
        Pdst[(size_t)ch2 * 512 +
             (size_t)(((kr2 >> 3) * 16 + c) << 3) + (kr2 & 7)] = f2bf(pnew);
    }
}

// ---------------------------------------------------------------------------
// conv GEMM via MFMA, split precision (hh + hl + lh): M=1024, N=4609, K=320.
// grid (37, 16): wave owns mt, 8 ic-tile accumulators.
__global__ __launch_bounds__(256) void k_conv(const bfrag8* __restrict__ CfH,
                                              const bfrag8* __restrict__ CfL,
                                              const bfrag8* __restrict__ PmcH,
                                              const bfrag8* __restrict__ PmcL,
                                              const float* __restrict__ PcolB,
                                              float* __restrict__ theta) {
    const int tid = threadIdx.x, lane = tid & 63, w = tid >> 6;
    const int icg = blockIdx.x;
    const int mt  = blockIdx.y * 4 + w;
    const int icmax = NIB - icg * 8;    // valid ic tiles in this block (>=1)

    f32x4 acc[8];
#pragma unroll
    for (int t8 = 0; t8 < 8; t8++) acc[t8] = (f32x4){0.f, 0.f, 0.f, 0.f};

#pragma unroll 1
    for (int kc = 0; kc < 10; kc++) {
        bfrag8 ah = CfH[(size_t)(kc * 64 + mt) * 64 + lane];
        bfrag8 al = CfL[(size_t)(kc * 64 + mt) * 64 + lane];
#pragma unroll
        for (int t8 = 0; t8 < 8; t8++) {
            if (t8 < icmax) {
                size_t bo = (size_t)(kc * NIB + icg * 8 + t8) * 64 + lane;
                bfrag8 bh = PmcH[bo];
                bfrag8 bl = PmcL[bo];
                acc[t8] = __builtin_amdgcn_mfma_f32_16x16x32_bf16(ah, bh, acc[t8], 0, 0, 0);
                acc[t8] = __builtin_amdgcn_mfma_f32_16x16x32_bf16(ah, bl, acc[t8], 0, 0, 0);
                acc[t8] = __builtin_amdgcn_mfma_f32_16x16x32_bf16(al, bh, acc[t8], 0, 0, 0);
            }
        }
    }

    const int n = lane & 15, gg = lane >> 4;
#pragma unroll
    for (int t8 = 0; t8 < 8; t8++) {
        if (t8 < icmax) {
            int i = (icg * 8 + t8) * 16 + n;
            if (i < N_TH) {
#pragma unroll
                for (int r = 0; r < 4; r++) {
                    int bt = mt * 16 + gg * 4 + r;
                    int t = bt & 31;
                    theta[(size_t)bt * TSTR + i] = acc[t8][r] + PcolB[(size_t)t * 4624 + i];
                }
            }
        }
    }
}

// ---------------------------------------------------------------------------
__global__ __launch_bounds__(256) void k_mlp(const float* __restrict__ xs,
                                             const float* __restrict__ ts,
                                             const float* __restrict__ theta,
                                             float* __restrict__ out) {
    const int tid  = threadIdx.x;
    const int lane = tid & 63;
    const int half = (lane >> 5) & 1;
    const int o    = lane & 31;
    const int wv   = tid >> 6;
    const int bt   = blockIdx.x * 8 + wv * 2 + half;
    const int b = bt >> 5, t = bt & 31;
    const float* th = theta + (size_t)bt * TSTR;

    float u[10];
    u[0] = ts[b * NL + t];
#pragma unroll
    for (int d = 0; d < 9; d++) u[1 + d] = xs[(b * NL + t) * 9 + d];

    float acc = th[320 + o];
#pragma unroll
    for (int i = 0; i < 10; i++) acc = fmaf(th[o * 10 + i], u[i], acc);
    float h = fmaxf(acc, 0.f);

#pragma unroll
    for (int l = 0; l < 4; l++) {
        int base = 352 + l * 1056;
        float a2 = th[base + 1024 + o];
#pragma unroll
        for (int i = 0; i < 32; i++)
            a2 = fmaf(th[base + o * 32 + i], __shfl(h, i, 32), a2);
        h = fmaxf(a2, 0.f);
    }

    float contrib = th[4576 + o] * h;
#pragma unroll
    for (int m = 16; m >= 1; m >>= 1) contrib += __shfl_xor(contrib, m, 32);
    if (o == 0) out[bt] = contrib + th[4608];
}

// ---------------------------------------------------------------------------
extern "C" void kernel_launch(void* const* d_in, const int* in_sizes, int n_in,
                              void* d_out, int out_size, void* d_ws, size_t ws_size,
                              hipStream_t stream) {
    const float* xs  = (const float*)d_in[0];
    const float* ts  = (const float*)d_in[1];
    const float* A   = (const float*)d_in[2];
    const float* Bm  = (const float*)d_in[3];
    const float* th0 = (const float*)d_in[4];
    float* out = (float*)d_out;
    float* ws  = (float*)d_ws;

    float*          Prow  = ws + OF_PROW;
    unsigned short* Pmf   = (unsigned short*)(ws + OF_PMF);
    float*          part  = ws + OF_PART;
    float*          PcolB = ws + OF_PCOLB;
    unsigned short* PmcH  = (unsigned short*)(ws + OF_PMCH);
    unsigned short* PmcL  = (unsigned short*)(ws + OF_PMCL);
    unsigned short* CfH   = (unsigned short*)(ws + OF_CFH);
    unsigned short* CfL   = (unsigned short*)(ws + OF_CFL);
    unsigned short* A2m   = (unsigned short*)(ws + OF_A2M);
    float*          theta = ws + OF_A2M;   // aliases A2m (dead after scan)

    k_p0<<<304, 256, 0, stream>>>(th0, Bm, Prow, Pmf, PmcH, PmcL);
    k_cf<<<1280, 256, 0, stream>>>(xs, ts, CfH, CfL);
    k_tr<<<10982, 256, 0, stream>>>(A, A2m);

    for (int k = 1; k <= 32; k++) {
        const unsigned short* src = Pmf + (size_t)((k - 1) & 1) * (NKC * 512);
        unsigned short* dst       = Pmf + (size_t)(k & 1) * (NKC * 512);
        k_stepK<<<dim3(NIB, 4), 256, 0, stream>>>((const bfrag8*)A2m, (const bfrag8*)src, part);
        k_fin<<<NIB, 256, 0, stream>>>(part, Prow, PcolB, PmcH, PmcL, dst, k);
    }

    k_conv<<<dim3(37, 16), 256, 0, stream>>>((const bfrag8*)CfH, (const bfrag8*)CfL,
                                             (const bfrag8*)PmcH, (const bfrag8*)PmcL,
                                             PcolB, theta);
    k_mlp<<<128, 256, 0, stream>>>(xs, ts, theta, out);
}